// Round 6
// baseline (1552.033 us; speedup 1.0000x reference)
//
#include <hip/hip_runtime.h>
#include <hip/hip_bf16.h>

// CensorNet T=512,B=256,I=128,H=256 GRU scan + BCE decode.
// R10: fully-overlapped fusion. One worker kernel, 64 blocks x 512 threads
// (8 waves, 2/SIMD, VGPR cap 256). Per 8-step chunk, each wave runs its scan
// step AND one 8-MFMA slice of the NEXT chunk's x@Wih GEMM between the same
// light per-step barriers -- the bf16 GEMM MFMAs fill the scan's VALU/LDS
// tail on the matrix pipe instead of serializing (R9's mistake). gi lives
// only in LDS (double-buffered, 98KB); A-frags prefetched from L2 one step
// ahead; x staged issue-early/write-late. No gi HBM traffic, no xconv/gemm1
// kernels. All MFMA fragment orders + epilogue expressions verbatim from the
// R7 pipeline -> bit-identical h trajectory; absmax 0.0 expected.

typedef __bf16 bf16x8_t __attribute__((ext_vector_type(8)));
typedef float floatx4_t __attribute__((ext_vector_type(4)));
typedef int intx4_t __attribute__((ext_vector_type(4)));
typedef unsigned int u32;
typedef u32 u32x4_t __attribute__((ext_vector_type(4)));

#define SW 2032.0f
#define SH 127.0f
#define INV_S (1.0f / (127.0f * 2032.0f))
#define NL2E (-1.44269504088896f) /* -log2(e) */
#define CRZ (NL2E * INV_S)
#define CN (2.0f * NL2E * INV_S)

static __device__ inline u32 pack2bf(float a, float b) {
  __bf16 x = (__bf16)a, y = (__bf16)b;
  unsigned short ux = *(unsigned short*)&x, uy = *(unsigned short*)&y;
  return (u32)ux | ((u32)uy << 16);
}

// ---------------- prep: quantize W_hh/W_dec to i8, Wih->bf16 --------------
__global__ void prep_kernel(const float* __restrict__ Whh,
                            const float* __restrict__ Wdec,
                            const float* __restrict__ Wih,
                            char* __restrict__ Wq, char* __restrict__ wdq,
                            __bf16* __restrict__ Wihb,
                            float* __restrict__ out) {
  int idx = blockIdx.x * 256 + threadIdx.x;  // 65536 total
  for (int i = idx; i < 768 * 256; i += 65536) {
    int v = (int)rintf(Whh[i] * SW);
    v = v > 127 ? 127 : (v < -127 ? -127 : v);
    Wq[i] = (char)v;
  }
  for (int i = idx; i < 768 * 128; i += 65536) Wihb[i] = (__bf16)Wih[i];
  if (idx < 256) {
    int v = (int)rintf(Wdec[idx] * SW);
    v = v > 127 ? 127 : (v < -127 ? -127 : v);
    wdq[idx] = (char)v;
  }
  if (idx == 0) out[0] = 0.f;
}

// ---------------- fused: overlapped gi-GEMM + serial scan -----------------
__global__ __launch_bounds__(512, 2) void fused_kernel(
    const char* __restrict__ Wq,      // [768][256] i8
    const char* __restrict__ wdq,     // [256] i8
    const float* __restrict__ x,      // [512][256][128] fp32
    const float* __restrict__ gt,     // [512][256]
    const float* __restrict__ bdec, const float* __restrict__ bhh,
    const float* __restrict__ bih,
    const __bf16* __restrict__ Wihb,  // [768][128] bf16
    float* __restrict__ out) {
  __shared__ u32 gi_s[2][8][3][512];  // 98304 B: [buf][tl][gate][dword]
  __shared__ __bf16 xs[2][32][136];   // 17408 B: [buf][tl*4+jb][k]
  __shared__ char hb[2][4][288];      //  2304 B: h i8 ping-pong
  __shared__ float lp[2][4][32];      //  1024 B: decoder partials (exact)

  const int tid = threadIdx.x;
  const int w = tid >> 6, lane = tid & 63;  // wave 0..7
  const int q = lane >> 4, nh = lane & 15;  // q = batch row 0..3
  const int g = blockIdx.x;                 // batch slice 0..63 (4 rows)
  const int col0 = w * 32 + nh;             // scan: lane's two h cols
  const int col1 = col0 + 16;

  // scan weights: wave owns cols w*32..+31 x 3 gates (B-operand, R7 layout)
  intx4_t wf[6][4];
#pragma unroll
  for (int c = 0; c < 3; ++c)
#pragma unroll
    for (int ss = 0; ss < 2; ++ss) {
      const int n = c * 256 + w * 32 + ss * 16 + nh;
#pragma unroll
      for (int kb = 0; kb < 4; ++kb)
        wf[c * 2 + ss][kb] =
            *(const intx4_t*)(Wq + (size_t)n * 256 + kb * 64 + q * 16);
    }
  // decoder: waves 4..7 own one k-block each (one per SIMD, exact partials)
  intx4_t wdfk;
  {
    const int kb = (w >= 4) ? (w - 4) : 0;
    intx4_t z = {0, 0, 0, 0};
    intx4_t v = *(const intx4_t*)(wdq + kb * 64 + q * 16);
    wdfk = (nh == 0) ? v : z;
  }

  const float bn20 = 2.0f * NL2E * bhh[512 + col0];
  const float bn21 = 2.0f * NL2E * bhh[512 + col1];
  const float bdec0 = bdec[0];

  for (int i2 = tid; i2 < 576; i2 += 512) ((u32*)hb)[i2] = 0;  // h0 = 0
  float ho0 = 0.f, ho1 = 0.f, loss = 0.f, gto = 0.f;

  // ---- GEMM helpers (wave owns n-pairs p = w*3 + {0,1,2}) ----
  const int xrow = tid >> 4, xcc = (tid & 15) * 8;  // x staging coords
  floatx4_t xr0, xr1;
  auto XISSUE = [&](int cc2) {  // issue x global loads for chunk cc2
    const size_t gx =
        ((size_t)(cc2 * 8 + (xrow >> 2)) * 256 + g * 4 + (xrow & 3)) * 128 +
        xcc;
    xr0 = *(const floatx4_t*)(x + gx);
    xr1 = *(const floatx4_t*)(x + gx + 4);
  };
  auto XWRITE = [&](int cc2) {  // convert + LDS write (after compute)
    bf16x8_t tv;
#pragma unroll
    for (int j = 0; j < 4; ++j) {
      tv[j] = (__bf16)xr0[j];
      tv[4 + j] = (__bf16)xr1[j];
    }
    *(bf16x8_t*)&xs[cc2 & 1][xrow][xcc] = tv;
  };
  auto ALOAD = [&](int j6, bf16x8_t(&A)[8]) {  // prefetch Wih frags (L2)
    const int p = w * 3 + (j6 >> 1);
    const int gate = p >> 3, wrec = p & 7;
    const __bf16* base =
        Wihb + (size_t)(gate * 256 + wrec * 32 + nh) * 128 + q * 8;
#pragma unroll
    for (int ss = 0; ss < 2; ++ss)
#pragma unroll
      for (int kk = 0; kk < 4; ++kk)
        A[ss * 4 + kk] = *(const bf16x8_t*)(base + ss * 2048 + kk * 32);
  };
  auto JOB = [&](int cnext, int j6, bf16x8_t(&A)[8]) {  // 8 MFMA + epilogue
    const int p = w * 3 + (j6 >> 1);
    const int gate = p >> 3, wrec = p & 7;
    const int m = j6 & 1;
    floatx4_t a0, a1;
#pragma unroll
    for (int j = 0; j < 4; ++j) {
      a0[j] = 0.f;
      a1[j] = 0.f;
    }
#pragma unroll
    for (int kk = 0; kk < 4; ++kk) {
      bf16x8_t B = *(const bf16x8_t*)&xs[cnext & 1][m * 16 + nh][kk * 32 + q * 8];
      a0 = __builtin_amdgcn_mfma_f32_16x16x32_bf16(A[kk], B, a0, 0, 0, 0);
      a1 = __builtin_amdgcn_mfma_f32_16x16x32_bf16(A[4 + kk], B, a1, 0, 0, 0);
    }
    const int n0 = gate * 256 + wrec * 32 + q * 4;
    floatx4_t biasA = *(const floatx4_t*)(bih + n0);
    floatx4_t biasB = *(const floatx4_t*)(bih + n0 + 16);
    if (gate < 2) {
      floatx4_t c1 = *(const floatx4_t*)(bhh + n0);
      floatx4_t c2 = *(const floatx4_t*)(bhh + n0 + 16);
#pragma unroll
      for (int j = 0; j < 4; ++j) {
        biasA[j] += c1[j];
        biasB[j] += c2[j];
      }
    }
    const float sc = (gate < 2) ? NL2E : (2.0f * NL2E);
    const int rowm = m * 16 + nh;
    u32x4_t pv;
#pragma unroll
    for (int j = 0; j < 4; ++j)
      pv[j] = pack2bf((a0[j] + biasA[j]) * sc, (a1[j] + biasB[j]) * sc);
    *(u32x4_t*)&gi_s[cnext & 1][rowm >> 2][gate][wrec * 64 + (rowm & 3) * 16 +
                                                 q * 4] = pv;
  };

  bf16x8_t Abuf0[8], Abuf1[8];

  // ---- prologue: chunk 0 gi serial, chunk 1 x staged, chunk1-job0 A ----
  __syncthreads();  // hb zeros visible
  XISSUE(0);
  XWRITE(0);
  __syncthreads();  // xs[0] ready
#pragma unroll 1
  for (int j6 = 0; j6 < 6; ++j6) {
    ALOAD(j6, Abuf0);
    JOB(0, j6, Abuf0);
  }
  XISSUE(1);
  XWRITE(1);
  ALOAD(0, Abuf0);  // chunk 1, job 0
  __syncthreads();  // gi_s[0] + xs[1] ready

#pragma unroll 1
  for (int c = 0; c < 64; ++c) {
    // BCE for chunk c-1 (lp[(c-1)&1] complete; writers now use lp[c&1])
    if (c > 0 && w == 0 && lane < 32) {
      const int gidx = (c - 1) * 8 + (lane >> 2) - 1;
      if (gidx >= 0) {
        const int cp = (c - 1) & 1;
        float l = (lp[cp][0][lane] + lp[cp][1][lane] + lp[cp][2][lane] +
                   lp[cp][3][lane]) * INV_S + bdec0;
        float t1 = log1pf(__expf(-fabsf(l)));
        loss += gto * (fmaxf(-l, 0.f) + t1) +
                (1.f - gto) * (fmaxf(l, 0.f) + t1);
      }
    }
    const int nsteps = (c == 63) ? 7 : 8;
    const bool dg = (c < 63);
#pragma unroll 1
    for (int tl = 0; tl < nsteps; ++tl) {
      if (tl == 0) {
        if (w == 0 && lane < 32)
          gto = gt[(size_t)(c * 8 + (lane >> 2)) * 256 + g * 4 + (lane & 3)];
        if (c + 2 <= 63) XISSUE(c + 2);
      }

      const int t = c * 8 + tl, pb = t & 1;
      intx4_t hbf[4];  // A-operand: row m holds h[m>>2] (broadcast)
#pragma unroll
      for (int kb = 0; kb < 4; ++kb)
        hbf[kb] = *(const intx4_t*)&hb[pb][nh >> 2][kb * 64 + q * 16];
      const u32 G0 = gi_s[c & 1][tl][0][w * 64 + lane];
      const u32 G1 = gi_s[c & 1][tl][1][w * 64 + lane];
      const u32 G2 = gi_s[c & 1][tl][2][w * 64 + lane];

      intx4_t acc[6];
#pragma unroll
      for (int cs = 0; cs < 6; ++cs)
#pragma unroll
        for (int jj = 0; jj < 4; ++jj) acc[cs][jj] = 0;
#pragma unroll
      for (int kb = 0; kb < 4; ++kb)
#pragma unroll
        for (int cs = 0; cs < 6; ++cs)
          acc[cs] = __builtin_amdgcn_mfma_i32_16x16x64_i8(hbf[kb], wf[cs][kb],
                                                          acc[cs], 0, 0, 0);
      // decoder partial (waves 4..7, one per SIMD)
      if (w >= 4) {
        intx4_t facc = {0, 0, 0, 0};
        facc = __builtin_amdgcn_mfma_i32_16x16x64_i8(hbf[w - 4], wdfk, facc,
                                                     0, 0, 0);
        if (nh == 0) lp[c & 1][w - 4][tl * 4 + q] = (float)facc[0];
      }
      // overlapped GEMM slice for chunk c+1 (static A-buffer by parity)
      if (dg && tl < 6) {
        if (tl & 1) {
          JOB(c + 1, tl, Abuf1);
          if (tl < 5)
            ALOAD(tl + 1, Abuf0);
          else if (c + 1 < 63)
            ALOAD(0, Abuf0);  // chunk c+2, job 0
        } else {
          JOB(c + 1, tl, Abuf0);
          ALOAD(tl + 1, Abuf1);
        }
      }
      if (tl == 6 && c + 2 <= 63) XWRITE(c + 2);

      // gate VALU (verbatim R7)
      const float gr0 = __uint_as_float(G0 << 16);
      const float gr1 = __uint_as_float(G0 & 0xffff0000u);
      const float gz0 = __uint_as_float(G1 << 16);
      const float gz1 = __uint_as_float(G1 & 0xffff0000u);
      const float an0 = __uint_as_float(G2 << 16);
      const float an1 = __uint_as_float(G2 & 0xffff0000u);
      float rr0 = __builtin_amdgcn_rcpf(
          1.f + __builtin_amdgcn_exp2f((float)acc[0][0] * CRZ + gr0));
      float rr1 = __builtin_amdgcn_rcpf(
          1.f + __builtin_amdgcn_exp2f((float)acc[1][0] * CRZ + gr1));
      float zz0 = __builtin_amdgcn_rcpf(
          1.f + __builtin_amdgcn_exp2f((float)acc[2][0] * CRZ + gz0));
      float zz1 = __builtin_amdgcn_rcpf(
          1.f + __builtin_amdgcn_exp2f((float)acc[3][0] * CRZ + gz1));
      float hn20 = (float)acc[4][0] * CN + bn20;
      float hn21 = (float)acc[5][0] * CN + bn21;
      float tv0 = 2.f * __builtin_amdgcn_rcpf(
                            1.f + __builtin_amdgcn_exp2f(rr0 * hn20 + an0)) -
                  1.f;
      float tv1 = 2.f * __builtin_amdgcn_rcpf(
                            1.f + __builtin_amdgcn_exp2f(rr1 * hn21 + an1)) -
                  1.f;
      float hnew0 = tv0 + zz0 * (ho0 - tv0);
      float hnew1 = tv1 + zz1 * (ho1 - tv1);
      ho0 = hnew0;
      ho1 = hnew1;
      int h0 = (int)rintf(hnew0 * SH);
      int h1 = (int)rintf(hnew1 * SH);
      hb[1 - pb][q][col0] = (char)h0;
      hb[1 - pb][q][col1] = (char)h1;

      // light barrier: drain LDS only; global prefetches stay in flight
      asm volatile("s_waitcnt lgkmcnt(0)" ::: "memory");
      __builtin_amdgcn_s_barrier();
      asm volatile("" ::: "memory");
    }
  }

  // tail: decoder partials of the final state (t=510 wrote hb[1])
  if (w >= 4) {
    intx4_t b2 = *(const intx4_t*)&hb[1][nh >> 2][(w - 4) * 64 + q * 16];
    intx4_t f2 = {0, 0, 0, 0};
    f2 = __builtin_amdgcn_mfma_i32_16x16x64_i8(b2, wdfk, f2, 0, 0, 0);
    if (nh == 0) lp[1][w - 4][7 * 4 + q] = (float)f2[0];
  }
  __syncthreads();
  // BCE for chunk 63 (slots 0..6 in-loop + tail slot 7; gidx 503..510)
  if (w == 0 && lane < 32) {
    float l = (lp[1][0][lane] + lp[1][1][lane] + lp[1][2][lane] +
               lp[1][3][lane]) * INV_S + bdec0;
    float t1 = log1pf(__expf(-fabsf(l)));
    loss += gto * (fmaxf(-l, 0.f) + t1) + (1.f - gto) * (fmaxf(l, 0.f) + t1);
  }
  if (w == 0) {
    loss += __shfl_xor(loss, 1);
    loss += __shfl_xor(loss, 2);
    loss += __shfl_xor(loss, 4);
    loss += __shfl_xor(loss, 8);
    loss += __shfl_xor(loss, 16);
    loss += __shfl_xor(loss, 32);
    if (lane == 0) atomicAdd(out, loss);
  }
}

// ---------------- host ----------------
extern "C" void kernel_launch(void* const* d_in, const int* in_sizes, int n_in,
                              void* d_out, int out_size, void* d_ws,
                              size_t ws_size, hipStream_t stream) {
  const float* x = (const float*)d_in[0];     // [512,256,128]
  const float* gt = (const float*)d_in[1];    // [512,256,1]
  const float* Wih = (const float*)d_in[2];   // [768,128]
  const float* Whh = (const float*)d_in[3];   // [768,256]
  const float* bih = (const float*)d_in[4];   // [768]
  const float* bhh = (const float*)d_in[5];   // [768]
  const float* Wdec = (const float*)d_in[6];  // [1,256]
  const float* bdec = (const float*)d_in[7];  // [1]
  float* out = (float*)d_out;

  char* ws = (char*)d_ws;
  char* Wq = ws;                          // 196608 B
  char* wdq = ws + 196608;                // 256 B (pad 512)
  __bf16* Wihb = (__bf16*)(ws + 197120);  // 196608 B

  prep_kernel<<<256, 256, 0, stream>>>(Whh, Wdec, Wih, Wq, wdq, Wihb, out);
  fused_kernel<<<64, 512, 0, stream>>>(Wq, wdq, x, gt, bdec, bhh, bih, Wihb,
                                       out);
}

// Round 7
// 523.661 us; speedup vs baseline: 2.9638x; 2.9638x over previous
//
#include <hip/hip_runtime.h>
#include <hip/hip_bf16.h>

// CensorNet T=512,B=256,I=128,H=256 GRU scan + BCE decode.
// R11: consolidate to R8 (rec_kernel byte-identical, 359us) + LDS-free gemm
// for the K=128 x@Wih GEMM: Wih fragments live in registers (loaded once per
// block, reused across 8 b-tiles), x fragments read direct from global
// (L2/L3-resident, 6-way reuse). Kills the staging-latency bottleneck that
// made the 128x128 LDS-tile structure pathological at K=128 (64KB staged per
// 64 MFMA/wave). Fragment values, kk order, epilogue expressions verbatim
// from R8's gemm1 -> bit-identical gi -> absmax 0.0 expected.
// R6/R9/R10 lesson (journal): producer-consumer and GEMM-into-scan fusion
// all regress (cross-XCD fences / serialization / VGPR spill). Closed.

typedef __bf16 bf16x8_t __attribute__((ext_vector_type(8)));
typedef float floatx4_t __attribute__((ext_vector_type(4)));
typedef int intx4_t __attribute__((ext_vector_type(4)));
typedef unsigned int u32;
typedef u32 u32x4_t __attribute__((ext_vector_type(4)));

#define SW 2032.0f
#define SH 127.0f
#define INV_S (1.0f / (127.0f * 2032.0f))
#define NL2E (-1.44269504088896f) /* -log2(e) */
#define CRZ (NL2E * INV_S)
#define CN (2.0f * NL2E * INV_S)

static __device__ inline u32 pack2bf(float a, float b) {
  __bf16 x = (__bf16)a, y = (__bf16)b;
  unsigned short ux = *(unsigned short*)&x, uy = *(unsigned short*)&y;
  return (u32)ux | ((u32)uy << 16);
}

// ---------------- prep: quantize W_hh/W_dec to i8, Wih->bf16, zero --------
__global__ void prep_kernel(const float* __restrict__ Whh,
                            const float* __restrict__ Wdec,
                            const float* __restrict__ Wih,
                            char* __restrict__ Wq, char* __restrict__ wdq,
                            __bf16* __restrict__ Wihb,
                            float* __restrict__ h_ws, float* __restrict__ out) {
  int idx = blockIdx.x * 256 + threadIdx.x;  // 65536 total
  for (int i = idx; i < 768 * 256; i += 65536) {
    int v = (int)rintf(Whh[i] * SW);
    v = v > 127 ? 127 : (v < -127 ? -127 : v);
    Wq[i] = (char)v;
  }
  for (int i = idx; i < 768 * 128; i += 65536) Wihb[i] = (__bf16)Wih[i];
  if (idx < 256) {
    int v = (int)rintf(Wdec[idx] * SW);
    v = v > 127 ? 127 : (v < -127 ? -127 : v);
    wdq[idx] = (char)v;
  }
  if (idx < 65536) h_ws[idx] = 0.f;
  if (idx == 0) out[0] = 0.f;
}

// ---------------- xconv: fp32 x chunk -> bf16 -----------------------------
__global__ __launch_bounds__(256) void xconv_kernel(const float* __restrict__ x,
                                                    __bf16* __restrict__ xb) {
  const size_t i = ((size_t)blockIdx.x * 256 + threadIdx.x) * 8;
  floatx4_t a = *(const floatx4_t*)(x + i);
  floatx4_t b = *(const floatx4_t*)(x + i + 4);
  bf16x8_t t;
#pragma unroll
  for (int j = 0; j < 4; ++j) {
    t[j] = (__bf16)a[j];
    t[4 + j] = (__bf16)b[j];
  }
  *(bf16x8_t*)(xb + i) = t;
}

// ---------------- gemm2: LDS-free gi GEMM (K=128) -------------------------
// gi layout (dword = bf16 pair for cols ss=0/ss=1, 16 apart):
//   U = (((t*64 + gg)*3 + gate)*8 + wrec)*64 + jb*16 + q*4 (+j)
// Pre-scaling: r,z: NL2E*(gi+bih+bhh); n: 2*NL2E*(gi+bih).
// Block: bx = n-tile (0..5, gate = bx>>1); by covers 8 b-tiles of 128.
__global__ __launch_bounds__(256, 2) void gemm2_kernel(
    const __bf16* __restrict__ xb,    // [tc*256][128] bf16
    const __bf16* __restrict__ Wihb,  // [768][128] bf16
    const float* __restrict__ bih, const float* __restrict__ bhh,
    u32* __restrict__ giw, int tc) {
  const int tid = threadIdx.x;
  const int w = tid >> 6, lane = tid & 63;
  const int q = lane >> 4, nh = lane & 15;
  const int n0 = blockIdx.x * 128;
  const int wm = w >> 1, wn = w & 1;

  // Wih fragments: register-resident, one-time load (values identical to
  // R8's As[wm*64+mt*16+nh][kk*32+q*8]).
  bf16x8_t af[4][4];
#pragma unroll
  for (int mt = 0; mt < 4; ++mt)
#pragma unroll
    for (int kk = 0; kk < 4; ++kk)
      af[mt][kk] = *(const bf16x8_t*)(Wihb +
                                      (size_t)(n0 + wm * 64 + mt * 16 + nh) *
                                          128 +
                                      kk * 32 + q * 8);

  // epilogue constants (invariant across b-tiles)
  const int gate = n0 >> 8;
  const float sc = (gate < 2) ? NL2E : (2.0f * NL2E);
  const int wr_base = ((n0 & 255) >> 5) + wm * 2;
  floatx4_t biasA[2], biasB[2];
#pragma unroll
  for (int a = 0; a < 2; ++a) {
    const int nnA = n0 + wm * 64 + a * 32 + q * 4;
    biasA[a] = *(const floatx4_t*)(bih + nnA);
    biasB[a] = *(const floatx4_t*)(bih + nnA + 16);
    if (gate < 2) {
      floatx4_t c1 = *(const floatx4_t*)(bhh + nnA);
      floatx4_t c2 = *(const floatx4_t*)(bhh + nnA + 16);
#pragma unroll
      for (int j = 0; j < 4; ++j) {
        biasA[a][j] += c1[j];
        biasB[a][j] += c2[j];
      }
    }
  }

  const int ntiles = tc * 2;
#pragma unroll 1
  for (int it = 0; it < 8; ++it) {
    const int bt = blockIdx.y * 8 + it;
    if (bt >= ntiles) break;
    const int ts = bt >> 1, b0 = (bt & 1) * 128;

    floatx4_t acc[4][4];
#pragma unroll
    for (int a = 0; a < 4; ++a)
#pragma unroll
      for (int b = 0; b < 4; ++b)
#pragma unroll
        for (int j = 0; j < 4; ++j) acc[a][b][j] = 0.f;

#pragma unroll
    for (int kk = 0; kk < 4; ++kk) {
      bf16x8_t bf[4];
#pragma unroll
      for (int nt = 0; nt < 4; ++nt)
        bf[nt] = *(const bf16x8_t*)(xb +
                                    (size_t)(ts * 256 + b0 + wn * 64 +
                                             nt * 16 + nh) *
                                        128 +
                                    kk * 32 + q * 8);
#pragma unroll
      for (int mt = 0; mt < 4; ++mt)
#pragma unroll
        for (int nt = 0; nt < 4; ++nt)
          acc[mt][nt] = __builtin_amdgcn_mfma_f32_16x16x32_bf16(
              af[mt][kk], bf[nt], acc[mt][nt], 0, 0, 0);
    }

    // epilogue: verbatim expressions from R8 gemm1
#pragma unroll
    for (int a = 0; a < 2; ++a) {
      const int wrec = wr_base + a;
#pragma unroll
      for (int nt = 0; nt < 4; ++nt) {
        const int bb = b0 + wn * 64 + nt * 16 + nh;  // 0..255 within step
        const int gg = bb >> 2, jb = bb & 3;
        size_t U = (((size_t)ts * 64 + gg) * 3 + gate) * 512 + wrec * 64 +
                   jb * 16 + q * 4;
        u32x4_t pv;
#pragma unroll
        for (int j = 0; j < 4; ++j)
          pv[j] = pack2bf((acc[2 * a][nt][j] + biasA[a][j]) * sc,
                          (acc[2 * a + 1][nt][j] + biasB[a][j]) * sc);
        *(u32x4_t*)(giw + U) = pv;
      }
    }
  }
}

// ---------------- rec: serial scan, 16 waves, replicated-A i8 MFMA --------
// (byte-identical to R8; 359us, MfmaUtil 11.7%, bank conflicts 0)
__global__ __launch_bounds__(1024) void rec_kernel(
    const char* __restrict__ Wq,   // [768][256] i8
    const char* __restrict__ wdq,  // [256] i8
    const u32* __restrict__ gi,    // pre-scaled bf16-pair units
    const float* __restrict__ gt, const float* __restrict__ bdec,
    const float* __restrict__ bhh, float* __restrict__ h_ws,
    float* __restrict__ out, int t0, int tc) {
  __shared__ char hb[2][4][288];  // h i8 ping-pong; stride 288 (2-way free)
  __shared__ float lp[4][2048];   // decoder partials (kb 0..3), exact ints

  const int tid = threadIdx.x;
  const int w = tid >> 6, lane = tid & 63;  // wave 0..15
  const int q = lane >> 4, nh = lane & 15;  // q = batch row 0..3
  const int g = blockIdx.x;                 // batch slice 0..63 (4 rows)
  const int col = w * 16 + nh;              // this lane's single h col
  const int wp = w >> 1;                    // gi dword group
  const int hi = w & 1;                     // lo/hi bf16 half (wave-uniform)

  // W_hh fragments (i8, B-operand): wave owns cols w*16..+15 for 3 gates
  intx4_t wf[3][4];
#pragma unroll
  for (int c = 0; c < 3; ++c) {
    const int n = c * 256 + col;
#pragma unroll
    for (int kb = 0; kb < 4; ++kb)
      wf[c][kb] = *(const intx4_t*)(Wq + (size_t)n * 256 + kb * 64 + q * 16);
  }
  // Wdec fragment: wave 12+kb owns k-block kb (one per SIMD)
  intx4_t wdfk;
  {
    const int kb = (w >= 12) ? (w - 12) : 0;
    intx4_t z = {0, 0, 0, 0};
    intx4_t v = *(const intx4_t*)(wdq + kb * 64 + q * 16);
    wdfk = (nh == 0) ? v : z;  // B col 0 = Wdec
  }

  const float bn2 = 2.0f * NL2E * bhh[512 + col];
  const float bdec0 = bdec[0];

  // stage initial h rows 0..3 quantized (256 words)
  if (tid < 256) {
    const int rr = tid >> 6, c0 = (tid & 63) * 4;
    u32 p = 0;
#pragma unroll
    for (int j = 0; j < 4; ++j) {
      int a = (int)rintf(h_ws[(size_t)(g * 4 + rr) * 256 + c0 + j] * SH);
      a = a > 127 ? 127 : (a < -127 ? -127 : a);
      p |= ((u32)(a & 255)) << (8 * j);
    }
    *(u32*)&hb[0][rr][c0] = p;
  }
  float ho = h_ws[(size_t)(g * 4 + q) * 256 + col];
  __syncthreads();

  const int tcm1 = tc - 1;
  const size_t boff = (size_t)wp * 64 + q * 16 + nh;
  // depth-2 prefetch register sets
  u32 GA[3], GB[3];
  {
    size_t u0 = ((size_t)g * 3) * 512 + boff;
#pragma unroll
    for (int c = 0; c < 3; ++c) GA[c] = gi[u0 + c * 512];
    const int t1s = tc > 1 ? 1 : 0;
    size_t u1 = (((size_t)t1s * 64 + g) * 3) * 512 + boff;
#pragma unroll
    for (int c = 0; c < 3; ++c) GB[c] = gi[u1 + c * 512];
  }

  // one GRU step: consumes G (gi of step T), then refills G from step TPRE
  auto STEP = [&](int T, u32* G, int TPRE) {
    const int pb = T & 1;
    intx4_t hbf[4];  // A-operand: row m holds h[m>>2] (4-lane broadcast)
#pragma unroll
    for (int kb = 0; kb < 4; ++kb)
      hbf[kb] = *(const intx4_t*)&hb[pb][nh >> 2][kb * 64 + q * 16];

    // extract old G (issued ~2 steps ago), then refill for step T+2
    float gv0, gv1, gv2;
    if (hi) {
      gv0 = __uint_as_float(G[0] & 0xffff0000u);
      gv1 = __uint_as_float(G[1] & 0xffff0000u);
      gv2 = __uint_as_float(G[2] & 0xffff0000u);
    } else {
      gv0 = __uint_as_float(G[0] << 16);
      gv1 = __uint_as_float(G[1] << 16);
      gv2 = __uint_as_float(G[2] << 16);
    }
    {
      size_t up = (((size_t)TPRE * 64 + g) * 3) * 512 + boff;
#pragma unroll
      for (int c = 0; c < 3; ++c) G[c] = gi[up + c * 512];
    }

    intx4_t acc[3];
#pragma unroll
    for (int cs = 0; cs < 3; ++cs)
#pragma unroll
      for (int jj = 0; jj < 4; ++jj) acc[cs][jj] = 0;

#pragma unroll
    for (int kb = 0; kb < 4; ++kb)
#pragma unroll
      for (int cs = 0; cs < 3; ++cs)
        acc[cs] = __builtin_amdgcn_mfma_i32_16x16x64_i8(hbf[kb], wf[cs][kb],
                                                        acc[cs], 0, 0, 0);
    // acc[cs][0] = gh[batch q][col] for gate cs -- in-register.

    // decoder partial: waves 12..15, one k-block each (one per SIMD)
    if (w >= 12) {
      intx4_t hsel = (w == 12) ? hbf[0]
                   : (w == 13) ? hbf[1]
                   : (w == 14) ? hbf[2] : hbf[3];
      intx4_t facc = {0, 0, 0, 0};
      facc = __builtin_amdgcn_mfma_i32_16x16x64_i8(hsel, wdfk, facc, 0, 0, 0);
      if (nh == 0 && T >= 1) lp[w - 12][(T - 1) * 4 + q] = (float)facc[0];
    }

    float rr0 = __builtin_amdgcn_rcpf(
        1.f + __builtin_amdgcn_exp2f((float)acc[0][0] * CRZ + gv0));
    float zz0 = __builtin_amdgcn_rcpf(
        1.f + __builtin_amdgcn_exp2f((float)acc[1][0] * CRZ + gv1));
    float hn2 = (float)acc[2][0] * CN + bn2;
    float tv0 = 2.f * __builtin_amdgcn_rcpf(
                          1.f + __builtin_amdgcn_exp2f(rr0 * hn2 + gv2)) -
                1.f;
    float hnew = tv0 + zz0 * (ho - tv0);
    ho = hnew;
    int h8 = (int)rintf(hnew * SH);
    hb[1 - pb][q][col] = (char)h8;

    // light barrier: drain LDS only; gi prefetch stays in flight
    asm volatile("s_waitcnt lgkmcnt(0)" ::: "memory");
    __builtin_amdgcn_s_barrier();
    asm volatile("" ::: "memory");
  };

  int t = 0;
#pragma unroll 1
  for (; t + 1 < tc; t += 2) {
    STEP(t, GA, (t + 2 <= tcm1) ? t + 2 : tcm1);
    STEP(t + 1, GB, (t + 3 <= tcm1) ? t + 3 : tcm1);
  }
  if (t < tc) STEP(t, GA, tcm1);

  // tail: decoder partials of final state
  if (w >= 12) {
    const int kb = w - 12;
    intx4_t b = *(const intx4_t*)&hb[tc & 1][nh >> 2][kb * 64 + q * 16];
    intx4_t fac2 = {0, 0, 0, 0};
    fac2 = __builtin_amdgcn_mfma_i32_16x16x64_i8(b, wdfk, fac2, 0, 0, 0);
    if (nh == 0) lp[kb][(tc - 1) * 4 + q] = (float)fac2[0];
  }
  __syncthreads();

  // bulk BCE sweep (partial sums are exact: each < 2^20, sum < 2^23)
  float loss = 0.f;
  for (int i = tid; i < tc * 4; i += 1024) {
    float l = (lp[0][i] + lp[1][i] + lp[2][i] + lp[3][i]) * INV_S + bdec0;
    float gtv = gt[(size_t)(t0 + (i >> 2) + 1) * 256 + g * 4 + (i & 3)];
    float t1 = log1pf(__expf(-fabsf(l)));
    loss += gtv * (fmaxf(-l, 0.f) + t1) + (1.f - gtv) * (fmaxf(l, 0.f) + t1);
  }
  loss += __shfl_xor(loss, 1);
  loss += __shfl_xor(loss, 2);
  loss += __shfl_xor(loss, 4);
  loss += __shfl_xor(loss, 8);
  loss += __shfl_xor(loss, 16);
  loss += __shfl_xor(loss, 32);
  if (lane == 0) atomicAdd(out, loss);

  // persist h (fp32) for next chunk
  h_ws[(size_t)(g * 4 + q) * 256 + col] = ho;
}

// ---------------- host ----------------
extern "C" void kernel_launch(void* const* d_in, const int* in_sizes, int n_in,
                              void* d_out, int out_size, void* d_ws,
                              size_t ws_size, hipStream_t stream) {
  const float* x = (const float*)d_in[0];     // [512,256,128]
  const float* gt = (const float*)d_in[1];    // [512,256,1]
  const float* Wih = (const float*)d_in[2];   // [768,128]
  const float* Whh = (const float*)d_in[3];   // [768,256]
  const float* bih = (const float*)d_in[4];   // [768]
  const float* bhh = (const float*)d_in[5];   // [768]
  const float* Wdec = (const float*)d_in[6];  // [1,256]
  const float* bdec = (const float*)d_in[7];  // [1]
  float* out = (float*)d_out;

  char* ws = (char*)d_ws;
  char* Wq = ws;                          // 196608 B
  char* wdq = ws + 196608;                // 512 B (256 used)
  float* h_ws = (float*)(ws + 197120);    // 262144 B
  __bf16* Wihb = (__bf16*)(ws + 459264);  // 196608 B
  char* dyn = ws + 655872;
  const size_t per_step = (size_t)393216 + 65536;  // gi + xb per time step
  size_t avail = ws_size > 655872 ? ws_size - 655872 : per_step;
  int Tc = (int)(avail / per_step);
  if (Tc < 1) Tc = 1;
  if (Tc > 511) Tc = 511;
  __bf16* xb = (__bf16*)dyn;                        // Tc*65536 B
  u32* gi = (u32*)(dyn + (size_t)Tc * 65536);       // Tc*393216 B

  prep_kernel<<<256, 256, 0, stream>>>(Whh, Wdec, Wih, Wq, wdq, Wihb, h_ws,
                                       out);
  for (int t0 = 0; t0 < 511; t0 += Tc) {
    const int tc = (511 - t0 < Tc) ? (511 - t0) : Tc;
    xconv_kernel<<<tc * 16, 256, 0, stream>>>(x + (size_t)t0 * 256 * 128, xb);
    gemm2_kernel<<<dim3(6, (tc * 2 + 7) / 8), 256, 0, stream>>>(xb, Wihb, bih,
                                                                bhh, gi, tc);
    rec_kernel<<<64, 1024, 0, stream>>>(Wq, wdq, gi, gt, bdec, bhh, h_ws, out,
                                        t0, tc);
  }
}